// Round 6
// baseline (538.551 us; speedup 1.0000x reference)
//
#include <hip/hip_runtime.h>
#include <hip/hip_bf16.h>

typedef __hip_bfloat16 bf16;
typedef __attribute__((ext_vector_type(8))) short short8;
typedef __attribute__((ext_vector_type(4))) float float4_;

#define DEV static __device__ __forceinline__

DEV float blo(unsigned w){ return __uint_as_float(w << 16); }
DEV float bhi(unsigned w){ return __uint_as_float(w & 0xffff0000u); }
DEV unsigned short f2bu(float x){ bf16 h = __float2bfloat16(x); unsigned short u; __builtin_memcpy(&u, &h, 2); return u; }
DEV unsigned pack2(float a, float b){ return (unsigned)f2bu(a) | ((unsigned)f2bu(b) << 16); }

DEV float gelu_tanh(float x){
  float z = 0.7978845608028654f * (x + 0.044715f * x * x * x);
  float th = 2.0f / (1.0f + __expf(-2.0f * z)) - 1.0f;
  return 0.5f * x * (1.0f + th);
}

// Dims: B=8, K=512, C=256, HEADS=8, D=32, N=64, FF=1024, HT=9; rows r=b*512+k, M=4096.

// ---------------------------------------------------------------- prep: bf16 convert + transposes + fused score-weight product
// blocks 0-15 WoT | 16-79 W1T | 80-143 W2T | 144-175 WvP | 176-239 query_bf | 240-2287 WqkT+bias_qk
__global__ __launch_bounds__(256) void k_prep(
    const float* __restrict__ query, const float* __restrict__ Wq,
    const float* __restrict__ Wk, const float* __restrict__ Wv,
    const float* __restrict__ Wo, const float* __restrict__ W1, const float* __restrict__ W2,
    const float* __restrict__ bq,
    bf16* __restrict__ query_bf, bf16* __restrict__ WqkT, float* __restrict__ bias_qk,
    bf16* __restrict__ WvP, bf16* __restrict__ WoT, bf16* __restrict__ W1T, bf16* __restrict__ W2T)
{
  __shared__ ushort ts[64][72];
  __shared__ float wkS[32];
  const int t = threadIdx.x;
  const int bx = blockIdx.x;

  if (bx < 144){
    // 64x64 tile transpose: out[n0+rr][k0+cc] = in[k0+r][n0+c]
    const float* src; bf16* dst; int ldi, ldo, kt, nt;
    if (bx < 16)      { src = Wo; dst = WoT; ldi = 256;  ldo = 256;  kt = bx & 3;        nt = bx >> 2; }
    else if (bx < 80) { src = W1; dst = W1T; ldi = 1024; ldo = 256;  kt = (bx-16) & 3;   nt = (bx-16) >> 2; }
    else              { src = W2; dst = W2T; ldi = 256;  ldo = 1024; kt = (bx-80) & 15;  nt = (bx-80) >> 4; }
    int k0 = kt * 64, n0 = nt * 64;
    {
      int r = t >> 2, c0 = (t & 3) * 16;
      #pragma unroll
      for (int g = 0; g < 4; g++){
        float4 v = *(const float4*)&src[(size_t)(k0 + r)*ldi + n0 + c0 + g*4];
        ts[r][c0+g*4+0] = f2bu(v.x); ts[r][c0+g*4+1] = f2bu(v.y);
        ts[r][c0+g*4+2] = f2bu(v.z); ts[r][c0+g*4+3] = f2bu(v.w);
      }
    }
    __syncthreads();
    {
      int rr = t >> 2, cc0 = (t & 3) * 16;
      unsigned wbuf[8];
      #pragma unroll
      for (int j = 0; j < 8; j++)
        wbuf[j] = (unsigned)ts[cc0+2*j][rr] | ((unsigned)ts[cc0+2*j+1][rr] << 16);
      uint4* d = (uint4*)(dst + (size_t)(n0 + rr)*ldo + k0 + cc0);
      d[0] = make_uint4(wbuf[0], wbuf[1], wbuf[2], wbuf[3]);
      d[1] = make_uint4(wbuf[4], wbuf[5], wbuf[6], wbuf[7]);
    }
  } else if (bx < 176){
    // WvP[h][d][c] = Wv[c][h*32+d]; tile: 64 c-rows x 32 d
    int idx = bx - 144, h = idx >> 2, kt = idx & 3, k0 = kt * 64;
    {
      int r = t >> 2, d0 = (t & 3) * 8;
      #pragma unroll
      for (int g = 0; g < 2; g++){
        float4 v = *(const float4*)&Wv[(size_t)(k0 + r)*256 + h*32 + d0 + g*4];
        ts[r][d0+g*4+0] = f2bu(v.x); ts[r][d0+g*4+1] = f2bu(v.y);
        ts[r][d0+g*4+2] = f2bu(v.z); ts[r][d0+g*4+3] = f2bu(v.w);
      }
    }
    __syncthreads();
    {
      int d = t >> 3, cc0 = (t & 7) * 8;
      unsigned wbuf[4];
      #pragma unroll
      for (int j = 0; j < 4; j++)
        wbuf[j] = (unsigned)ts[cc0+2*j][d] | ((unsigned)ts[cc0+2*j+1][d] << 16);
      *(uint4*)(WvP + (size_t)h*8192 + (size_t)d*256 + k0 + cc0) =
          make_uint4(wbuf[0], wbuf[1], wbuf[2], wbuf[3]);
    }
  } else if (bx < 240){
    int off = (bx - 176) * 16384;
    #pragma unroll
    for (int g = 0; g < 16; g++){
      int i = off + g*1024 + t*4;
      float4 v = *(const float4*)&query[i];
      *(uint2*)(query_bf + i) = make_uint2(pack2(v.x, v.y), pack2(v.z, v.w));
    }
  } else {
    // fused score weight: block -> (h, c); thread t -> e
    int idx = bx - 240, h = idx >> 8, c = idx & 255;
    if (t < 32) wkS[t] = Wk[(size_t)c*256 + h*32 + t];
    __syncthreads();
    float acc = 0.f;
    const float* wq = Wq + (size_t)t*256 + h*32;
    #pragma unroll
    for (int d = 0; d < 32; d++) acc += wq[d] * wkS[d];
    WqkT[(size_t)(h*256 + c)*256 + t] = __float2bfloat16(acc);
    if (t == 0){
      float bacc = 0.f;
      #pragma unroll
      for (int d = 0; d < 32; d++) bacc += bq[h*32 + d] * wkS[d];
      bias_qk[h*256 + c] = bacc;
    }
  }
}

// ---------------------------------------------------------------- MFMA GEMM: C[m][n] = A[m][k] . BT[n][k]
// Tile 64 x NT, 4 waves. Double-buffered LDS staging (T14: load-early/store-late),
// one barrier per K-step. EPI: 0=bf16 bias, 2=bf16 bias+gelu. KDIM%64==0.
template<int KDIM, int NT, int EPI>
__global__ __launch_bounds__(256) void k_gemm(
    const bf16* __restrict__ A, int lda, int acolH,
    const bf16* __restrict__ BT, int btH,
    const float* __restrict__ bias,
    bf16* __restrict__ Cb, int ldc, int ncolH)
{
  constexpr int KB = 64;
  constexpr int LP = KB + 8;
  constexpr int ASEG = KB / 8;          // 8 segs of 8 bf16
  constexpr int NKS = KDIM / KB;
  constexpr int AIT = (64*ASEG)/256;    // uint4 items per thread (A)
  constexpr int BIT = (NT*ASEG)/256;    // uint4 items per thread (B)
  __shared__ short As[2][64][LP];
  __shared__ short Bs[2][NT][LP];

  const int t = threadIdx.x;
  const int w = t >> 6, l = t & 63, lm = l & 15, lq = l >> 4;
  const int m0 = blockIdx.x * 64;
  const int h = blockIdx.z;
  const size_t acol = (size_t)h * acolH;
  const bf16* Bt = BT + (size_t)h * btH + (size_t)(blockIdx.y * NT) * KDIM;
  const int ncol = h * ncolH + blockIdx.y * NT;

  float4_ acc[NT/16];
  #pragma unroll
  for (int i = 0; i < NT/16; i++) acc[i] = (float4_){0.f,0.f,0.f,0.f};

  uint4 ra[AIT], rb[BIT];
  auto loadAB = [&](int k0){
    #pragma unroll
    for (int j = 0; j < AIT; j++){
      int i = t + j*256, row = i / ASEG, seg = i % ASEG;
      ra[j] = *(const uint4*)(A + (size_t)(m0+row)*lda + acol + k0 + seg*8);
    }
    #pragma unroll
    for (int j = 0; j < BIT; j++){
      int i = t + j*256, row = i / ASEG, seg = i % ASEG;
      rb[j] = *(const uint4*)(Bt + (size_t)row*KDIM + k0 + seg*8);
    }
  };
  auto storeAB = [&](int buf){
    #pragma unroll
    for (int j = 0; j < AIT; j++){
      int i = t + j*256, row = i / ASEG, seg = i % ASEG;
      *(uint4*)&As[buf][row][seg*8] = ra[j];
    }
    #pragma unroll
    for (int j = 0; j < BIT; j++){
      int i = t + j*256, row = i / ASEG, seg = i % ASEG;
      *(uint4*)&Bs[buf][row][seg*8] = rb[j];
    }
  };

  loadAB(0);
  storeAB(0);
  __syncthreads();
  for (int ks = 0; ks < NKS; ks++){
    int cur = ks & 1;
    if (ks + 1 < NKS) loadAB((ks+1)*KB);   // issue next-step globals before MFMA
    #pragma unroll
    for (int kk = 0; kk < KB/32; kk++){
      short8 af = *(const short8*)&As[cur][w*16 + lm][kk*32 + lq*8];
      #pragma unroll
      for (int nt = 0; nt < NT/16; nt++){
        short8 bfr = *(const short8*)&Bs[cur][nt*16 + lm][kk*32 + lq*8];
        acc[nt] = __builtin_amdgcn_mfma_f32_16x16x32_bf16(af, bfr, acc[nt], 0, 0, 0);
      }
    }
    if (ks + 1 < NKS){
      storeAB(cur ^ 1);                    // other buffer: safe vs this step's readers
      __syncthreads();
    }
  }

  #pragma unroll
  for (int nt = 0; nt < NT/16; nt++){
    int gcol = ncol + nt*16 + lm;
    float bb = bias ? bias[gcol] : 0.0f;
    #pragma unroll
    for (int rg = 0; rg < 4; rg++){
      int row = m0 + w*16 + lq*4 + rg;
      float v = acc[nt][rg] + bb;
      if (EPI == 0) Cb[(size_t)row*ldc + gcol] = __float2bfloat16(v);
      else          Cb[(size_t)row*ldc + gcol] = __float2bfloat16(gelu_tanh(v));
    }
  }
}

// ---------------------------------------------------------------- fused MFMA GEMM (16x256 tile) + bias + resid + LayerNorm
// Double-buffered staging, one barrier per K-step.
template<int KDIM, int WRITE_BF>
__global__ __launch_bounds__(256) void k_gemm_ln(
    const bf16* __restrict__ A, int lda,
    const bf16* __restrict__ BT,          // [256][KDIM]
    const float* __restrict__ bias,
    const float* __restrict__ resid,      // [M][256]
    const float* __restrict__ gamma, const float* __restrict__ beta,
    float* __restrict__ Cf, bf16* __restrict__ Cb)
{
  constexpr int KB = 64, LP = 72;
  constexpr int NKS = KDIM / KB;
  __shared__ short As[2][16][LP];
  __shared__ short Bs[2][256][LP];
  __shared__ float2 part[4][16];

  const int t = threadIdx.x;
  const int w = t >> 6, l = t & 63, lm = l & 15, lq = l >> 4;
  const int m0 = blockIdx.x * 16;

  float4_ acc[4];
  #pragma unroll
  for (int i = 0; i < 4; i++) acc[i] = (float4_){0.f,0.f,0.f,0.f};

  uint4 ra;            // t<128: one A item (row=t>>3, seg=t&7)
  uint4 rb[8];         // 2048 B items / 256 threads
  auto loadAB = [&](int k0){
    if (t < 128){
      int row = t >> 3, seg = t & 7;
      ra = *(const uint4*)(A + (size_t)(m0+row)*lda + k0 + seg*8);
    }
    #pragma unroll
    for (int j = 0; j < 8; j++){
      int i = t + j*256, row = i >> 3, seg = i & 7;
      rb[j] = *(const uint4*)(BT + (size_t)row*KDIM + k0 + seg*8);
    }
  };
  auto storeAB = [&](int buf){
    if (t < 128){
      int row = t >> 3, seg = t & 7;
      *(uint4*)&As[buf][row][seg*8] = ra;
    }
    #pragma unroll
    for (int j = 0; j < 8; j++){
      int i = t + j*256, row = i >> 3, seg = i & 7;
      *(uint4*)&Bs[buf][row][seg*8] = rb[j];
    }
  };

  loadAB(0);
  storeAB(0);
  __syncthreads();
  for (int ks = 0; ks < NKS; ks++){
    int cur = ks & 1;
    if (ks + 1 < NKS) loadAB((ks+1)*KB);
    #pragma unroll
    for (int kk = 0; kk < 2; kk++){
      short8 af = *(const short8*)&As[cur][lm][kk*32 + lq*8];
      #pragma unroll
      for (int nt = 0; nt < 4; nt++){
        short8 bfr = *(const short8*)&Bs[cur][w*64 + nt*16 + lm][kk*32 + lq*8];
        acc[nt] = __builtin_amdgcn_mfma_f32_16x16x32_bf16(af, bfr, acc[nt], 0, 0, 0);
      }
    }
    if (ks + 1 < NKS){
      storeAB(cur ^ 1);
      __syncthreads();
    }
  }

  // epilogue: v = acc + bias + resid; LN over the 256 cols of each row
  float v[4][4];
  float s1[4] = {0,0,0,0}, s2[4] = {0,0,0,0};
  #pragma unroll
  for (int nt = 0; nt < 4; nt++){
    int col = w*64 + nt*16 + lm;
    float bb = bias[col];
    #pragma unroll
    for (int rg = 0; rg < 4; rg++){
      int row = m0 + lq*4 + rg;
      float x = acc[nt][rg] + bb + resid[(size_t)row*256 + col];
      v[nt][rg] = x;
      s1[rg] += x; s2[rg] += x*x;
    }
  }
  #pragma unroll
  for (int off = 1; off < 16; off <<= 1){
    #pragma unroll
    for (int rg = 0; rg < 4; rg++){
      s1[rg] += __shfl_xor(s1[rg], off);
      s2[rg] += __shfl_xor(s2[rg], off);
    }
  }
  if (lm == 0){
    #pragma unroll
    for (int rg = 0; rg < 4; rg++)
      part[w][lq*4 + rg] = make_float2(s1[rg], s2[rg]);
  }
  __syncthreads();
  #pragma unroll
  for (int rg = 0; rg < 4; rg++){
    int rl = lq*4 + rg;
    float S1 = part[0][rl].x + part[1][rl].x + part[2][rl].x + part[3][rl].x;
    float S2 = part[0][rl].y + part[1][rl].y + part[2][rl].y + part[3][rl].y;
    float mean = S1 * (1.0f/256.0f);
    float var  = S2 * (1.0f/256.0f) - mean*mean;
    float inv  = rsqrtf(var + 1e-5f);
    #pragma unroll
    for (int nt = 0; nt < 4; nt++){
      int col = w*64 + nt*16 + lm;
      float o = (v[nt][rg] - mean) * inv * gamma[col] + beta[col];
      size_t idx = (size_t)(m0 + rl)*256 + col;
      Cf[idx] = o;
      if (WRITE_BF) Cb[idx] = __float2bfloat16(o);
    }
  }
}

// ---------------------------------------------------------------- attention core per (b,k)
// Dual-layout LDS (both 128B-multiple rows + per-row XOR slot swizzle, T2):
//   fsT[n][c] for QK^T MFMA, fs[c][n] for PV MFMA. Softmax = verified round-2
//   pattern (per-head 32-lane half-wave), emitting swizzled bf16 attnT[h][n].
// Phases: stage -> bar -> scoreMFMA+dump -> bar -> softmax -> bar -> PV MFMA.
// LDS: fsT 32768 + fs 32768 + qkb 4352 + biasS 2176 + s_scT 2176 + attnT 2048 = 76288 B (2 blocks/CU)
__global__ __launch_bounds__(256) void k_attn(
    const float* __restrict__ local_feat, const float* __restrict__ local_spat,
    const float* __restrict__ rel_table, const bf16* __restrict__ qk,
    bf16* __restrict__ fctx)
{
  __shared__ __attribute__((aligned(16))) ushort fsT[64][256];  // [n][c ^ key(n)]
  __shared__ __attribute__((aligned(16))) ushort fs[256][64];   // [c][n ^ ((c&7)<<3)]
  __shared__ __attribute__((aligned(16))) ushort qkb[8][272];   // [h][c] bf16
  __shared__ __attribute__((aligned(16))) ushort attnT[16][64]; // [h][n ^ ((h&7)<<3)] bf16, rows 8-15 dup
  __shared__ __attribute__((aligned(16))) float biasS[8][68];   // [h][n]
  __shared__ __attribute__((aligned(16))) float s_scT[8][68];   // [h][n] scaled+biased scores

  const int t = threadIdx.x;
  const int r = blockIdx.x;
  const int b = r >> 9, k = r & 511;
  const int w = t >> 6, l = t & 63, lm = l & 15, lq = l >> 4;

  // ---- stage local_feat -> fs (row-major) AND fsT (transposed), bf16, swizzled
  {
    const int cpair = t >> 3;        // 0..31
    const int mrow  = t & 7;         // 0..7
    const int nq8   = mrow * 8;      // n start (slot-aligned)
    #pragma unroll
    for (int p = 0; p < 4; p++){
      int c0 = p*64 + cpair*2, c1 = c0 + 1;
      const float* s0 = local_feat + ((size_t)((b*256 + c0)*512 + k))*64 + nq8;
      const float* s1 = local_feat + ((size_t)((b*256 + c1)*512 + k))*64 + nq8;
      float4 a0 = *(const float4*)(s0);
      float4 a1 = *(const float4*)(s0 + 4);
      float4 b0 = *(const float4*)(s1);
      float4 b1 = *(const float4*)(s1 + 4);
      ushort u0[8] = { f2bu(a0.x), f2bu(a0.y), f2bu(a0.z), f2bu(a0.w),
                       f2bu(a1.x), f2bu(a1.y), f2bu(a1.z), f2bu(a1.w) };
      ushort u1[8] = { f2bu(b0.x), f2bu(b0.y), f2bu(b0.z), f2bu(b0.w),
                       f2bu(b1.x), f2bu(b1.y), f2bu(b1.z), f2bu(b1.w) };
      // fs rows (n-contiguous), b128 each
      {
        int sw0 = nq8 ^ ((c0 & 7) << 3);
        int sw1 = nq8 ^ ((c1 & 7) << 3);
        *(uint4*)&fs[c0][sw0] = make_uint4(
            (unsigned)u0[0] | ((unsigned)u0[1]<<16), (unsigned)u0[2] | ((unsigned)u0[3]<<16),
            (unsigned)u0[4] | ((unsigned)u0[5]<<16), (unsigned)u0[6] | ((unsigned)u0[7]<<16));
        *(uint4*)&fs[c1][sw1] = make_uint4(
            (unsigned)u1[0] | ((unsigned)u1[1]<<16), (unsigned)u1[2] | ((unsigned)u1[3]<<16),
            (unsigned)u1[4] | ((unsigned)u1[5]<<16), (unsigned)u1[6] | ((unsigned)u1[7]<<16));
      }
      // fsT rows (c-pair packed), b32 each; key mixes row>>3 so lanes spread banks
      #pragma unroll
      for (int i = 0; i < 8; i++){
        int key = ((mrow ^ i) & 7) << 3;
        *(unsigned*)&fsT[nq8 + i][c0 ^ key] = (unsigned)u0[i] | ((unsigned)u1[i] << 16);
      }
    }
  }
  // ---- stage qk row (already bf16) -> qkb rows 0..7
  {
    uint4 a = *(const uint4*)(qk + (size_t)r * 2048 + t * 8);
    int h = t >> 5, c0 = (t & 31) * 8;
    *(uint4*)&qkb[h][c0] = a;
  }
  // ---- grid-sample bias -> biasS (rel_table read from global, L1/L2-hot)
  if (t < 64){
    float2 sxy = *(const float2*)&local_spat[((size_t)r*64 + t)*2];
    float gx = (sxy.x + 1.0f) * 4.0f, gy = (sxy.y + 1.0f) * 4.0f;
    float x0f = floorf(gx), y0f = floorf(gy);
    int xi0 = (int)x0f, yi0 = (int)y0f;
    float wx1 = gx - x0f, wx0 = 1.0f - wx1;
    float wy1 = gy - y0f, wy0 = 1.0f - wy1;
    int xs[4] = {xi0, xi0 + 1, xi0, xi0 + 1};
    int ys[4] = {yi0, yi0, yi0 + 1, yi0 + 1};
    float wj[4] = {wy0*wx0, wy0*wx1, wy1*wx0, wy1*wx1};
    float ww[4]; int ix[4];
    #pragma unroll
    for (int j = 0; j < 4; j++){
      bool valid = (xs[j] >= 0) && (xs[j] <= 8) && (ys[j] >= 0) && (ys[j] <= 8);
      ix[j] = min(max(ys[j],0),8)*9 + min(max(xs[j],0),8);
      ww[j] = valid ? wj[j] : 0.0f;
    }
    #pragma unroll
    for (int h = 0; h < 8; h++){
      const float* th = rel_table + h*81;
      biasS[h][t] = th[ix[0]]*ww[0] + th[ix[1]]*ww[1] + th[ix[2]]*ww[2] + th[ix[3]]*ww[3];
    }
  }
  __syncthreads();

  // ---- score MFMA: wave w owns n-tile [w*16, w*16+16); D[n_local][h]
  {
    float4_ acc = (float4_){0.f,0.f,0.f,0.f};
    const int arow = w*16 + lm;
    const int akey = (((arow >> 3) ^ arow) & 7) << 3;
    #pragma unroll
    for (int ks = 0; ks < 8; ks++){
      short8 af  = *(const short8*)&fsT[arow][(ks*32 + lq*8) ^ akey];
      short8 bfr = *(const short8*)&qkb[lm & 7][ks*32 + lq*8];  // lm>=8 duplicates; cols 8-15 discarded
      acc = __builtin_amdgcn_mfma_f32_16x16x32_bf16(af, bfr, acc, 0, 0, 0);
    }
    if (lm < 8){
      const float scale = 0.17677669529663687f;
      int n0 = w*16 + lq*4;
      float4 sv;
      sv.x = acc[0]*scale + biasS[lm][n0+0];
      sv.y = acc[1]*scale + biasS[lm][n0+1];
      sv.z = acc[2]*scale + biasS[lm][n0+2];
      sv.w = acc[3]*scale + biasS[lm][n0+3];
      *(float4*)&s_scT[lm][n0] = sv;
    }
  }
  __syncthreads();

  // ---- softmax: each 32-lane half-wave owns one head (verified pattern)
  {
    int g = t >> 5, j = t & 31;
    float sc0 = s_scT[g][j], sc1 = s_scT[g][j+32];
    float m = fmaxf(sc0, sc1);
    #pragma unroll
    for (int off = 1; off < 32; off <<= 1) m = fmaxf(m, __shfl_xor(m, off));
    float e0 = __expf(sc0 - m), e1 = __expf(sc1 - m);
    float s = e0 + e1;
    #pragma unroll
    for (int off = 1; off < 32; off <<= 1) s += __shfl_xor(s, off);
    float inv = 1.0f / s;
    ushort p0 = f2bu(e0 * inv), p1 = f2bu(e1 * inv);
    int key = g << 3;
    attnT[g    ][j        ^ key] = p0;
    attnT[g    ][(j + 32) ^ key] = p1;
    attnT[g + 8][j        ^ key] = p0;   // dup so B-frag lanes 8-15 read defined data
    attnT[g + 8][(j + 32) ^ key] = p1;
  }
  __syncthreads();

  // ---- PV MFMA: D[c_local][h] = sum_n fs[c][n] * attnT[h][n]; wave w owns c-tiles 4w..4w+3
  {
    const int bkey = (lm & 7) << 3;
    short8 bf0 = *(const short8*)&attnT[lm][(      lq*8) ^ bkey];
    short8 bf1 = *(const short8*)&attnT[lm][(32 + lq*8) ^ bkey];
    #pragma unroll
    for (int ct = 0; ct < 4; ct++){
      int crow = (w*4 + ct)*16 + lm;
      int ckey = (crow & 7) << 3;
      float4_ acc2 = (float4_){0.f,0.f,0.f,0.f};
      short8 af0 = *(const short8*)&fs[crow][(      lq*8) ^ ckey];
      acc2 = __builtin_amdgcn_mfma_f32_16x16x32_bf16(af0, bf0, acc2, 0, 0, 0);
      short8 af1 = *(const short8*)&fs[crow][(32 + lq*8) ^ ckey];
      acc2 = __builtin_amdgcn_mfma_f32_16x16x32_bf16(af1, bf1, acc2, 0, 0, 0);
      if (lm < 8){
        int c = (w*4 + ct)*16 + lq*4;
        size_t base = (size_t)r*2048 + (size_t)lm*256 + c;
        *(uint2*)&fctx[base] = make_uint2(pack2(acc2[0], acc2[1]), pack2(acc2[2], acc2[3]));
      }
    }
  }
}

// ---------------------------------------------------------------- launch
extern "C" void kernel_launch(void* const* d_in, const int* in_sizes, int n_in,
                              void* d_out, int out_size, void* d_ws, size_t ws_size,
                              hipStream_t stream)
{
  const float* query      = (const float*)d_in[0];
  const float* local_feat = (const float*)d_in[1];
  const float* local_spat = (const float*)d_in[2];
  const float* rel_table  = (const float*)d_in[3];
  const float* Wq  = (const float*)d_in[4];   const float* bq  = (const float*)d_in[5];
  const float* Wk  = (const float*)d_in[6];
  const float* Wv  = (const float*)d_in[8];   const float* bv  = (const float*)d_in[9];
  const float* Wo  = (const float*)d_in[10];  const float* bo  = (const float*)d_in[11];
  const float* g1  = (const float*)d_in[12];  const float* be1 = (const float*)d_in[13];
  const float* W1  = (const float*)d_in[14];  const float* b1  = (const float*)d_in[15];
  const float* W2  = (const float*)d_in[16];  const float* b2  = (const float*)d_in[17];
  const float* g2  = (const float*)d_in[18];  const float* be2 = (const float*)d_in[19];

  char* ws = (char*)d_ws;
  bf16*  qk       = (bf16*)(ws + 0);           // 16 MB [4096][2048]
  bf16*  fctx     = (bf16*)(ws + 16777216);    // 16 MB [4096][2048]
  bf16*  query_bf = (bf16*)(ws + 33554432);    // 2 MB
  bf16*  WqkT     = (bf16*)(ws + 35651584);    // 1 MB  [2048][256]
  bf16*  WoT      = (bf16*)(ws + 36700160);    // 128 KB [256][256]
  bf16*  WvP      = (bf16*)(ws + 36831232);    // 128 KB [8][32][256]
  bf16*  W1T      = (bf16*)(ws + 36962304);    // 512 KB [1024][256]
  bf16*  W2T      = (bf16*)(ws + 37486592);    // 512 KB [256][1024]
  float* bias_qk  = (float*)(ws + 38010880);   // 8 KB  [2048]
  // phase-2 reuse (qk region dead after k_attn; fctx region dead after ctx gemm)
  bf16*  ctx_bf   = (bf16*)(ws + 0);           // 2 MB
  float* x        = (float*)(ws + 2097152);    // 4 MB
  bf16*  x_bf     = (bf16*)(ws + 6291456);     // 2 MB
  bf16*  h1       = (bf16*)(ws + 20971520);    // 8 MB
  float* out      = (float*)d_out;

  dim3 blk(256);
  k_prep<<<dim3(2288), blk, 0, stream>>>(query, Wq, Wk, Wv, Wo, W1, W2, bq,
                                         query_bf, WqkT, bias_qk, WvP, WoT, W1T, W2T);
  // qk[r, h*256+c] = query[r] . Wqk[:, h*256+c] + bias_qk  (fused q@Wq then .Wk)
  k_gemm<256,64,0><<<dim3(64,32,1), blk, 0, stream>>>(query_bf, 256, 0, WqkT, 0, bias_qk, qk, 2048, 0);
  k_attn<<<dim3(4096), blk, 0, stream>>>(local_feat, local_spat, rel_table, qk, fctx);
  // ctx[r, h*32+d] = fctx_h . Wv[:,h*32+d] + bv
  k_gemm<256,32,0><<<dim3(64,1,8), blk, 0, stream>>>(fctx, 2048, 256, WvP, 8192, bv, ctx_bf, 256, 32);
  // x = LN1(query + ctx @ Wo + bo)  (f32 + bf16)
  k_gemm_ln<256,1><<<dim3(256), blk, 0, stream>>>(ctx_bf, 256, WoT, bo, query, g1, be1, x, x_bf);
  // h1 = gelu(x @ W1 + b1)
  k_gemm<256,64,2><<<dim3(64,16,1), blk, 0, stream>>>(x_bf, 256, 0, W1T, 0, b1, h1, 1024, 0);
  // out = LN2(x + h1 @ W2 + b2)
  k_gemm_ln<1024,0><<<dim3(256), blk, 0, stream>>>(h1, 1024, W2T, b2, x, g2, be2, out, nullptr);
}

// Round 7
// 500.614 us; speedup vs baseline: 1.0758x; 1.0758x over previous
//
#include <hip/hip_runtime.h>
#include <hip/hip_bf16.h>

typedef __hip_bfloat16 bf16;
typedef __attribute__((ext_vector_type(8))) short short8;
typedef __attribute__((ext_vector_type(4))) float float4_;

#define DEV static __device__ __forceinline__

DEV float blo(unsigned w){ return __uint_as_float(w << 16); }
DEV float bhi(unsigned w){ return __uint_as_float(w & 0xffff0000u); }
DEV unsigned short f2bu(float x){ bf16 h = __float2bfloat16(x); unsigned short u; __builtin_memcpy(&u, &h, 2); return u; }
DEV unsigned pack2(float a, float b){ return (unsigned)f2bu(a) | ((unsigned)f2bu(b) << 16); }

DEV float gelu_tanh(float x){
  float z = 0.7978845608028654f * (x + 0.044715f * x * x * x);
  float th = 2.0f / (1.0f + __expf(-2.0f * z)) - 1.0f;
  return 0.5f * x * (1.0f + th);
}

// Dims: B=8, K=512, C=256, HEADS=8, D=32, N=64, FF=1024, HT=9; rows r=b*512+k, M=4096.

// ---------------------------------------------------------------- prep: coalesced bf16 convert + LDS-tiled transposes
// blocks 0-15 WqT | 16-31 WoT | 32-95 W1T | 96-159 W2T | 160-191 WvP | 192-199 WkP | 200-263 query_bf
__global__ __launch_bounds__(256) void k_prep(
    const float* __restrict__ query, const float* __restrict__ Wq,
    const float* __restrict__ Wk, const float* __restrict__ Wv,
    const float* __restrict__ Wo, const float* __restrict__ W1, const float* __restrict__ W2,
    bf16* __restrict__ query_bf, bf16* __restrict__ WqT, bf16* __restrict__ WkP,
    bf16* __restrict__ WvP, bf16* __restrict__ WoT, bf16* __restrict__ W1T, bf16* __restrict__ W2T)
{
  __shared__ ushort ts[64][72];
  const int t = threadIdx.x;
  const int bx = blockIdx.x;

  if (bx < 160){
    // 64x64 tile transpose: out[n0+rr][k0+cc] = in[k0+r][n0+c]
    const float* src; bf16* dst; int ldi, ldo, kt, nt;
    if (bx < 16)      { src = Wq; dst = WqT; ldi = 256;  ldo = 256;  kt = bx & 3;        nt = bx >> 2; }
    else if (bx < 32) { src = Wo; dst = WoT; ldi = 256;  ldo = 256;  kt = (bx-16) & 3;   nt = (bx-16) >> 2; }
    else if (bx < 96) { src = W1; dst = W1T; ldi = 1024; ldo = 256;  kt = (bx-32) & 3;   nt = (bx-32) >> 2; }
    else              { src = W2; dst = W2T; ldi = 256;  ldo = 1024; kt = (bx-96) & 15;  nt = (bx-96) >> 4; }
    int k0 = kt * 64, n0 = nt * 64;
    {
      int r = t >> 2, c0 = (t & 3) * 16;
      #pragma unroll
      for (int g = 0; g < 4; g++){
        float4 v = *(const float4*)&src[(size_t)(k0 + r)*ldi + n0 + c0 + g*4];
        ts[r][c0+g*4+0] = f2bu(v.x); ts[r][c0+g*4+1] = f2bu(v.y);
        ts[r][c0+g*4+2] = f2bu(v.z); ts[r][c0+g*4+3] = f2bu(v.w);
      }
    }
    __syncthreads();
    {
      int rr = t >> 2, cc0 = (t & 3) * 16;
      unsigned wbuf[8];
      #pragma unroll
      for (int j = 0; j < 8; j++)
        wbuf[j] = (unsigned)ts[cc0+2*j][rr] | ((unsigned)ts[cc0+2*j+1][rr] << 16);
      uint4* d = (uint4*)(dst + (size_t)(n0 + rr)*ldo + k0 + cc0);
      d[0] = make_uint4(wbuf[0], wbuf[1], wbuf[2], wbuf[3]);
      d[1] = make_uint4(wbuf[4], wbuf[5], wbuf[6], wbuf[7]);
    }
  } else if (bx < 192){
    // WvP[h][d][c] = Wv[c][h*32+d]; tile: 64 c-rows x 32 d
    int idx = bx - 160, h = idx >> 2, kt = idx & 3, k0 = kt * 64;
    {
      int r = t >> 2, d0 = (t & 3) * 8;
      #pragma unroll
      for (int g = 0; g < 2; g++){
        float4 v = *(const float4*)&Wv[(size_t)(k0 + r)*256 + h*32 + d0 + g*4];
        ts[r][d0+g*4+0] = f2bu(v.x); ts[r][d0+g*4+1] = f2bu(v.y);
        ts[r][d0+g*4+2] = f2bu(v.z); ts[r][d0+g*4+3] = f2bu(v.w);
      }
    }
    __syncthreads();
    {
      int d = t >> 3, cc0 = (t & 7) * 8;
      unsigned wbuf[4];
      #pragma unroll
      for (int j = 0; j < 4; j++)
        wbuf[j] = (unsigned)ts[cc0+2*j][d] | ((unsigned)ts[cc0+2*j+1][d] << 16);
      *(uint4*)(WvP + (size_t)h*8192 + (size_t)d*256 + k0 + cc0) =
          make_uint4(wbuf[0], wbuf[1], wbuf[2], wbuf[3]);
    }
  } else if (bx < 200){
    // WkP[h][c][d] = Wk[c][h*32+d] (coalesced slice copy)
    int off = (bx - 192) * 8192;
    #pragma unroll
    for (int g = 0; g < 8; g++){
      int i = off + g*1024 + t*4;
      int h = i >> 13, c = (i >> 5) & 255, d = i & 31;
      float4 v = *(const float4*)&Wk[(size_t)c*256 + h*32 + d];
      *(uint2*)(WkP + i) = make_uint2(pack2(v.x, v.y), pack2(v.z, v.w));
    }
  } else {
    int off = (bx - 200) * 16384;
    #pragma unroll
    for (int g = 0; g < 16; g++){
      int i = off + g*1024 + t*4;
      float4 v = *(const float4*)&query[i];
      *(uint2*)(query_bf + i) = make_uint2(pack2(v.x, v.y), pack2(v.z, v.w));
    }
  }
}

// ---------------------------------------------------------------- MFMA GEMM: C[m][n] = A[m][k] . BT[n][k]
// Tile 64 x NT, 4 waves. EPI: 0=bf16 bias, 2=bf16 bias+gelu.
template<int KDIM, int NT, int EPI>
__global__ __launch_bounds__(256) void k_gemm(
    const bf16* __restrict__ A, int lda, int acolH,
    const bf16* __restrict__ BT, int btH,
    const float* __restrict__ bias,
    bf16* __restrict__ Cb, int ldc, int ncolH)
{
  constexpr int KB = (KDIM >= 64) ? 64 : 32;
  constexpr int LP = KB + 8;
  constexpr int ASEG = KB / 8;
  __shared__ short As[64][LP];
  __shared__ short Bs[NT][LP];

  const int t = threadIdx.x;
  const int w = t >> 6, l = t & 63, lm = l & 15, lq = l >> 4;
  const int m0 = blockIdx.x * 64;
  const int h = blockIdx.z;
  const size_t acol = (size_t)h * acolH;
  const bf16* Bt = BT + (size_t)h * btH + (size_t)(blockIdx.y * NT) * KDIM;
  const int ncol = h * ncolH + blockIdx.y * NT;

  float4_ acc[NT/16];
  #pragma unroll
  for (int i = 0; i < NT/16; i++) acc[i] = (float4_){0.f,0.f,0.f,0.f};

  for (int k0 = 0; k0 < KDIM; k0 += KB){
    if (k0) __syncthreads();
    for (int i = t; i < 64*ASEG; i += 256){
      int row = i / ASEG, seg = i % ASEG;
      uint4 v = *(const uint4*)(A + (size_t)(m0+row)*lda + acol + k0 + seg*8);
      *(uint4*)&As[row][seg*8] = v;
    }
    for (int i = t; i < NT*ASEG; i += 256){
      int row = i / ASEG, seg = i % ASEG;
      uint4 v = *(const uint4*)(Bt + (size_t)row*KDIM + k0 + seg*8);
      *(uint4*)&Bs[row][seg*8] = v;
    }
    __syncthreads();
    #pragma unroll
    for (int kk = 0; kk < KB/32; kk++){
      short8 af = *(const short8*)&As[w*16 + lm][kk*32 + lq*8];
      #pragma unroll
      for (int nt = 0; nt < NT/16; nt++){
        short8 bfr = *(const short8*)&Bs[nt*16 + lm][kk*32 + lq*8];
        acc[nt] = __builtin_amdgcn_mfma_f32_16x16x32_bf16(af, bfr, acc[nt], 0, 0, 0);
      }
    }
  }

  #pragma unroll
  for (int nt = 0; nt < NT/16; nt++){
    int gcol = ncol + nt*16 + lm;
    float bb = bias ? bias[gcol] : 0.0f;
    #pragma unroll
    for (int rg = 0; rg < 4; rg++){
      int row = m0 + w*16 + lq*4 + rg;
      float v = acc[nt][rg] + bb;
      if (EPI == 0) Cb[(size_t)row*ldc + gcol] = __float2bfloat16(v);
      else          Cb[(size_t)row*ldc + gcol] = __float2bfloat16(gelu_tanh(v));
    }
  }
}

// ---------------------------------------------------------------- fused MFMA GEMM (16x256 tile) + bias + resid + LayerNorm
template<int KDIM, int WRITE_BF>
__global__ __launch_bounds__(256) void k_gemm_ln(
    const bf16* __restrict__ A, int lda,
    const bf16* __restrict__ BT,          // [256][KDIM]
    const float* __restrict__ bias,
    const float* __restrict__ resid,      // [M][256]
    const float* __restrict__ gamma, const float* __restrict__ beta,
    float* __restrict__ Cf, bf16* __restrict__ Cb)
{
  constexpr int KB = 64, LP = 72;
  __shared__ short As[16][LP];
  __shared__ short Bs[256][LP];
  __shared__ float2 part[4][16];

  const int t = threadIdx.x;
  const int w = t >> 6, l = t & 63, lm = l & 15, lq = l >> 4;
  const int m0 = blockIdx.x * 16;

  float4_ acc[4];
  #pragma unroll
  for (int i = 0; i < 4; i++) acc[i] = (float4_){0.f,0.f,0.f,0.f};

  for (int k0 = 0; k0 < KDIM; k0 += KB){
    if (k0) __syncthreads();
    if (t < 128){
      int row = t >> 3, seg = t & 7;
      uint4 v = *(const uint4*)(A + (size_t)(m0+row)*lda + k0 + seg*8);
      *(uint4*)&As[row][seg*8] = v;
    }
    for (int i = t; i < 2048; i += 256){
      int row = i >> 3, seg = i & 7;
      uint4 v = *(const uint4*)(BT + (size_t)row*KDIM + k0 + seg*8);
      *(uint4*)&Bs[row][seg*8] = v;
    }
    __syncthreads();
    #pragma unroll
    for (int kk = 0; kk < 2; kk++){
      short8 af = *(const short8*)&As[lm][kk*32 + lq*8];
      #pragma unroll
      for (int nt = 0; nt < 4; nt++){
        short8 bfr = *(const short8*)&Bs[w*64 + nt*16 + lm][kk*32 + lq*8];
        acc[nt] = __builtin_amdgcn_mfma_f32_16x16x32_bf16(af, bfr, acc[nt], 0, 0, 0);
      }
    }
  }

  // epilogue: v = acc + bias + resid; LN over the 256 cols of each row
  float v[4][4];
  float s1[4] = {0,0,0,0}, s2[4] = {0,0,0,0};
  #pragma unroll
  for (int nt = 0; nt < 4; nt++){
    int col = w*64 + nt*16 + lm;
    float bb = bias[col];
    #pragma unroll
    for (int rg = 0; rg < 4; rg++){
      int row = m0 + lq*4 + rg;
      float x = acc[nt][rg] + bb + resid[(size_t)row*256 + col];
      v[nt][rg] = x;
      s1[rg] += x; s2[rg] += x*x;
    }
  }
  #pragma unroll
  for (int off = 1; off < 16; off <<= 1){
    #pragma unroll
    for (int rg = 0; rg < 4; rg++){
      s1[rg] += __shfl_xor(s1[rg], off);
      s2[rg] += __shfl_xor(s2[rg], off);
    }
  }
  if (lm == 0){
    #pragma unroll
    for (int rg = 0; rg < 4; rg++)
      part[w][lq*4 + rg] = make_float2(s1[rg], s2[rg]);
  }
  __syncthreads();
  #pragma unroll
  for (int rg = 0; rg < 4; rg++){
    int rl = lq*4 + rg;
    float S1 = part[0][rl].x + part[1][rl].x + part[2][rl].x + part[3][rl].x;
    float S2 = part[0][rl].y + part[1][rl].y + part[2][rl].y + part[3][rl].y;
    float mean = S1 * (1.0f/256.0f);
    float var  = S2 * (1.0f/256.0f) - mean*mean;
    float inv  = rsqrtf(var + 1e-5f);
    #pragma unroll
    for (int nt = 0; nt < 4; nt++){
      int col = w*64 + nt*16 + lm;
      float o = (v[nt][rg] - mean) * inv * gamma[col] + beta[col];
      size_t idx = (size_t)(m0 + rl)*256 + col;
      Cf[idx] = o;
      if (WRITE_BF) Cb[idx] = __float2bfloat16(o);
    }
  }
}

// ---------------------------------------------------------------- attention core per (b,k)
// Dual-layout LDS (both 128B-multiple rows + per-row XOR slot swizzle, T2):
//   fsT[n][c] for QK^T MFMA, fs[c][n] for PV MFMA. Softmax = verified round-2
//   pattern (per-head 32-lane half-wave), emitting swizzled bf16 attnT[h][n].
// Phases: stage -> bar -> scoreMFMA+dump -> bar -> softmax -> bar -> PV MFMA.
// LDS: fsT 32768 + fs 32768 + qkb 4352 + biasS 2176 + s_scT 2176 + attnT 2048 = 76288 B (2 blocks/CU)
__global__ __launch_bounds__(256) void k_attn(
    const float* __restrict__ local_feat, const float* __restrict__ local_spat,
    const float* __restrict__ rel_table, const bf16* __restrict__ qk,
    bf16* __restrict__ fctx)
{
  __shared__ __attribute__((aligned(16))) ushort fsT[64][256];  // [n][c ^ key(n)]
  __shared__ __attribute__((aligned(16))) ushort fs[256][64];   // [c][n ^ ((c&7)<<3)]
  __shared__ __attribute__((aligned(16))) ushort qkb[8][272];   // [h][c] bf16
  __shared__ __attribute__((aligned(16))) ushort attnT[16][64]; // [h][n ^ ((h&7)<<3)] bf16, rows 8-15 dup
  __shared__ __attribute__((aligned(16))) float biasS[8][68];   // [h][n]
  __shared__ __attribute__((aligned(16))) float s_scT[8][68];   // [h][n] scaled+biased scores

  const int t = threadIdx.x;
  const int r = blockIdx.x;
  const int b = r >> 9, k = r & 511;
  const int w = t >> 6, l = t & 63, lm = l & 15, lq = l >> 4;

  // ---- stage local_feat -> fs (row-major) AND fsT (transposed), bf16, swizzled
  {
    const int cpair = t >> 3;        // 0..31
    const int mrow  = t & 7;         // 0..7
    const int nq8   = mrow * 8;      // n start (slot-aligned)
    #pragma unroll
    for (int p = 0; p < 4; p++){
      int c0 = p*64 + cpair*2, c1 = c0 + 1;
      const float* s0 = local_feat + ((size_t)((b*256 + c0)*512 + k))*64 + nq8;
      const float* s1 = local_feat + ((size_t)((b*256 + c1)*512 + k))*64 + nq8;
      float4 a0 = *(const float4*)(s0);
      float4 a1 = *(const float4*)(s0 + 4);
      float4 b0 = *(const float4*)(s1);
      float4 b1 = *(const float4*)(s1 + 4);
      ushort u0[8] = { f2bu(a0.x), f2bu(a0.y), f2bu(a0.z), f2bu(a0.w),
                       f2bu(a1.x), f2bu(a1.y), f2bu(a1.z), f2bu(a1.w) };
      ushort u1[8] = { f2bu(b0.x), f2bu(b0.y), f2bu(b0.z), f2bu(b0.w),
                       f2bu(b1.x), f2bu(b1.y), f2bu(b1.z), f2bu(b1.w) };
      // fs rows (n-contiguous), b128 each
      {
        int sw0 = nq8 ^ ((c0 & 7) << 3);
        int sw1 = nq8 ^ ((c1 & 7) << 3);
        *(uint4*)&fs[c0][sw0] = make_uint4(
            (unsigned)u0[0] | ((unsigned)u0[1]<<16), (unsigned)u0[2] | ((unsigned)u0[3]<<16),
            (unsigned)u0[4] | ((unsigned)u0[5]<<16), (unsigned)u0[6] | ((unsigned)u0[7]<<16));
        *(uint4*)&fs[c1][sw1] = make_uint4(
            (unsigned)u1[0] | ((unsigned)u1[1]<<16), (unsigned)u1[2] | ((unsigned)u1[3]<<16),
            (unsigned)u1[4] | ((unsigned)u1[5]<<16), (unsigned)u1[6] | ((unsigned)u1[7]<<16));
      }
      // fsT rows (c-pair packed), b32 each; key mixes row>>3 so lanes spread banks
      #pragma unroll
      for (int i = 0; i < 8; i++){
        int key = ((mrow ^ i) & 7) << 3;
        *(unsigned*)&fsT[nq8 + i][c0 ^ key] = (unsigned)u0[i] | ((unsigned)u1[i] << 16);
      }
    }
  }
  // ---- stage qk row (already bf16) -> qkb rows 0..7
  {
    uint4 a = *(const uint4*)(qk + (size_t)r * 2048 + t * 8);
    int h = t >> 5, c0 = (t & 31) * 8;
    *(uint4*)&qkb[h][c0] = a;
  }
  // ---- grid-sample bias -> biasS (rel_table read from global, L1/L2-hot)
  if (t < 64){
    float2 sxy = *(const float2*)&local_spat[((size_t)r*64 + t)*2];
    float gx = (sxy.x + 1.0f) * 4.0f, gy = (sxy.y + 1.0f) * 4.0f;
    float x0f = floorf(gx), y0f = floorf(gy);
    int xi0 = (int)x0f, yi0 = (int)y0f;
    float wx1 = gx - x0f, wx0 = 1.0f - wx1;
    float wy1 = gy - y0f, wy0 = 1.0f - wy1;
    int xs[4] = {xi0, xi0 + 1, xi0, xi0 + 1};
    int ys[4] = {yi0, yi0, yi0 + 1, yi0 + 1};
    float wj[4] = {wy0*wx0, wy0*wx1, wy1*wx0, wy1*wx1};
    float ww[4]; int ix[4];
    #pragma unroll
    for (int j = 0; j < 4; j++){
      bool valid = (xs[j] >= 0) && (xs[j] <= 8) && (ys[j] >= 0) && (ys[j] <= 8);
      ix[j] = min(max(ys[j],0),8)*9 + min(max(xs[j],0),8);
      ww[j] = valid ? wj[j] : 0.0f;
    }
    #pragma unroll
    for (int h = 0; h < 8; h++){
      const float* th = rel_table + h*81;
      biasS[h][t] = th[ix[0]]*ww[0] + th[ix[1]]*ww[1] + th[ix[2]]*ww[2] + th[ix[3]]*ww[3];
    }
  }
  __syncthreads();

  // ---- score MFMA: wave w owns n-tile [w*16, w*16+16); D[n_local][h]
  {
    float4_ acc = (float4_){0.f,0.f,0.f,0.f};
    const int arow = w*16 + lm;
    const int akey = (((arow >> 3) ^ arow) & 7) << 3;
    #pragma unroll
    for (int ks = 0; ks < 8; ks++){
      short8 af  = *(const short8*)&fsT[arow][(ks*32 + lq*8) ^ akey];
      short8 bfr = *(const short8*)&qkb[lm & 7][ks*32 + lq*8];  // lm>=8 duplicates; cols 8-15 discarded
      acc = __builtin_amdgcn_mfma_f32_16x16x32_bf16(af, bfr, acc, 0, 0, 0);
    }
    if (lm < 8){
      const float scale = 0.17677669529663687f;
      int n0 = w*16 + lq*4;
      float4 sv;
      sv.x = acc[0]*scale + biasS[lm][n0+0];
      sv.y = acc[1]*scale + biasS[lm][n0+1];
      sv.z = acc[2]*scale + biasS[lm][n0+2];
      sv.w = acc[3]*scale + biasS[lm][n0+3];
      *(float4*)&s_scT[lm][n0] = sv;
    }
  }
  __syncthreads();

  // ---- softmax: each 32-lane half-wave owns one head (verified pattern)
  {
    int g = t >> 5, j = t & 31;
    float sc0 = s_scT[g][j], sc1 = s_scT[g][j+32];
    float m = fmaxf(sc0, sc1);
    #pragma unroll
    for (int off = 1; off < 32; off <<= 1) m = fmaxf(m, __shfl_xor(m, off));
    float e0 = __expf(sc0 - m), e1 = __expf(sc1 - m);
    float s = e0 + e1;
    #pragma unroll
    for (int off = 1; off < 32; off <<= 1) s += __shfl_xor(s, off);
    float inv = 1.0f / s;
    ushort p0 = f2bu(e0 * inv), p1 = f2bu(e1 * inv);
    int key = g << 3;
    attnT[g    ][j        ^ key] = p0;
    attnT[g    ][(j + 32) ^ key] = p1;
    attnT[g + 8][j        ^ key] = p0;   // dup so B-frag lanes 8-15 read defined data
    attnT[g + 8][(j + 32) ^ key] = p1;
  }
  __syncthreads();

  // ---- PV MFMA: D[c_local][h] = sum_n fs[c][n] * attnT[h][n]; wave w owns c-tiles 4w..4w+3
  {
    const int bkey = (lm & 7) << 3;
    short8 bf0 = *(const short8*)&attnT[lm][(      lq*8) ^ bkey];
    short8 bf1 = *(const short8*)&attnT[lm][(32 + lq*8) ^ bkey];
    #pragma unroll
    for (int ct = 0; ct < 4; ct++){
      int crow = (w*4 + ct)*16 + lm;
      int ckey = (crow & 7) << 3;
      float4_ acc2 = (float4_){0.f,0.f,0.f,0.f};
      short8 af0 = *(const short8*)&fs[crow][(      lq*8) ^ ckey];
      acc2 = __builtin_amdgcn_mfma_f32_16x16x32_bf16(af0, bf0, acc2, 0, 0, 0);
      short8 af1 = *(const short8*)&fs[crow][(32 + lq*8) ^ ckey];
      acc2 = __builtin_amdgcn_mfma_f32_16x16x32_bf16(af1, bf1, acc2, 0, 0, 0);
      if (lm < 8){
        int c = (w*4 + ct)*16 + lq*4;
        size_t base = (size_t)r*2048 + (size_t)lm*256 + c;
        *(uint2*)&fctx[base] = make_uint2(pack2(acc2[0], acc2[1]), pack2(acc2[2], acc2[3]));
      }
    }
  }
}

// ---------------------------------------------------------------- launch
extern "C" void kernel_launch(void* const* d_in, const int* in_sizes, int n_in,
                              void* d_out, int out_size, void* d_ws, size_t ws_size,
                              hipStream_t stream)
{
  const float* query      = (const float*)d_in[0];
  const float* local_feat = (const float*)d_in[1];
  const float* local_spat = (const float*)d_in[2];
  const float* rel_table  = (const float*)d_in[3];
  const float* Wq  = (const float*)d_in[4];   const float* bq  = (const float*)d_in[5];
  const float* Wk  = (const float*)d_in[6];
  const float* Wv  = (const float*)d_in[8];   const float* bv  = (const float*)d_in[9];
  const float* Wo  = (const float*)d_in[10];  const float* bo  = (const float*)d_in[11];
  const float* g1  = (const float*)d_in[12];  const float* be1 = (const float*)d_in[13];
  const float* W1  = (const float*)d_in[14];  const float* b1  = (const float*)d_in[15];
  const float* W2  = (const float*)d_in[16];  const float* b2  = (const float*)d_in[17];
  const float* g2  = (const float*)d_in[18];  const float* be2 = (const float*)d_in[19];

  char* ws = (char*)d_ws;
  bf16*  qk       = (bf16*)(ws + 0);           // 16 MB [4096][2048]
  bf16*  fctx     = (bf16*)(ws + 16777216);    // 16 MB [4096][2048]
  bf16*  query_bf = (bf16*)(ws + 33554432);    // 2 MB
  bf16*  q_bf     = (bf16*)(ws + 35651584);    // 2 MB
  bf16*  WqT      = (bf16*)(ws + 37748736);    // 128 KB [256][256]
  bf16*  WkP      = (bf16*)(ws + 37879808);    // 128 KB [8][256][32]
  bf16*  WvP      = (bf16*)(ws + 38010880);    // 128 KB [8][32][256]
  bf16*  WoT      = (bf16*)(ws + 38141952);    // 128 KB [256][256]
  bf16*  W1T      = (bf16*)(ws + 38273024);    // 512 KB [1024][256]
  bf16*  W2T      = (bf16*)(ws + 38797312);    // 512 KB [256][1024]
  // phase-2 reuse (qk region dead after k_attn; fctx region dead after ctx gemm)
  bf16*  ctx_bf   = (bf16*)(ws + 0);           // 2 MB
  float* x        = (float*)(ws + 2097152);    // 4 MB
  bf16*  x_bf     = (bf16*)(ws + 6291456);     // 2 MB
  bf16*  h1       = (bf16*)(ws + 20971520);    // 8 MB
  float* out      = (float*)d_out;

  dim3 blk(256);
  k_prep<<<dim3(264), blk, 0, stream>>>(query, Wq, Wk, Wv, Wo, W1, W2,
                                        query_bf, WqT, WkP, WvP, WoT, W1T, W2T);
  // q = query @ Wq + bq
  k_gemm<256,64,0><<<dim3(64,4,1), blk, 0, stream>>>(query_bf, 256, 0, WqT, 0, bq, q_bf, 256, 0);
  // qk[r, h*256+c] = q_h . Wk_h[c,:]
  k_gemm<32,64,0><<<dim3(64,4,8), blk, 0, stream>>>(q_bf, 256, 32, WkP, 8192, nullptr, qk, 2048, 256);
  k_attn<<<dim3(4096), blk, 0, stream>>>(local_feat, local_spat, rel_table, qk, fctx);
  // ctx[r, h*32+d] = fctx_h . Wv[:,h*32+d] + bv
  k_gemm<256,32,0><<<dim3(64,1,8), blk, 0, stream>>>(fctx, 2048, 256, WvP, 8192, bv, ctx_bf, 256, 32);
  // x = LN1(query + ctx @ Wo + bo)  (f32 + bf16)
  k_gemm_ln<256,1><<<dim3(256), blk, 0, stream>>>(ctx_bf, 256, WoT, bo, query, g1, be1, x, x_bf);
  // h1 = gelu(x @ W1 + b1)
  k_gemm<256,64,2><<<dim3(64,16,1), blk, 0, stream>>>(x_bf, 256, 0, W1T, 0, b1, h1, 1024, 0);
  // out = LN2(x + h1 @ W2 + b2)
  k_gemm_ln<1024,0><<<dim3(256), blk, 0, stream>>>(h1, 1024, W2T, b2, x, g2, be2, out, nullptr);
}